// Round 1
// baseline (138.387 us; speedup 1.0000x reference)
//
#include <hip/hip_runtime.h>
#include <math.h>

#define N_NODES 2048

__device__ __forceinline__ float invdeg(int j) { return j > 0 ? 1.0f / (float)j : 0.0f; }

// K1: blocks 0..31: per-feature exclusive scan of x[i,f]^2/||x_i|| -> neigh1[:, f]
//     blocks 32..543: one wave per dst node j: neigh1[j, 32+k] = invdeg * sum_{i<j} c[i,k]*|c[i,k]-c[j,k]|
__global__ __launch_bounds__(256) void k_edgefeat(const float* __restrict__ x,
                                                  const float* __restrict__ cent,
                                                  float* __restrict__ n1) {
  __shared__ float invn_s[N_NODES];
  __shared__ float sc[256];
  const int tid = threadIdx.x;
  const int bx = blockIdx.x;
  if (bx < 32) {
    const int f = bx;
    // phase A: all 2048 inverse norms (redundant across blocks, trivial cost)
    for (int r = 0; r < 8; ++r) {
      int n = tid + 256 * r;
      const float4* xp = (const float4*)(x + n * 32);
      float s = 0.f;
#pragma unroll
      for (int q = 0; q < 8; ++q) {
        float4 v = xp[q];
        s += v.x * v.x + v.y * v.y + v.z * v.z + v.w * v.w;
      }
      invn_s[n] = rsqrtf(s);
    }
    __syncthreads();
    // phase B: exclusive scan over i of x[i,f]^2 * invn[i]; thread owns i in [8t, 8t+8)
    float sv[8], xv[8];
    float ts = 0.f;
#pragma unroll
    for (int r = 0; r < 8; ++r) {
      int i = tid * 8 + r;
      float xf = x[i * 32 + f];
      xv[r] = xf;
      float s = xf * xf * invn_s[i];
      sv[r] = s;
      ts += s;
    }
    sc[tid] = ts;
    __syncthreads();
    for (int off = 1; off < 256; off <<= 1) {
      float v = (tid >= off) ? sc[tid - off] : 0.f;
      __syncthreads();
      sc[tid] += v;
      __syncthreads();
    }
    float P = sc[tid] - ts;  // exclusive prefix of thread-chunk sums
#pragma unroll
    for (int r = 0; r < 8; ++r) {
      int i = tid * 8 + r;
      n1[i * 35 + f] = P * xv[r] * invn_s[i] * invdeg(i);
      P += sv[r];
    }
  } else {
    const int j = (bx - 32) * 4 + (tid >> 6);  // one wave per dst node
    const int lane = tid & 63;
    const float cj0 = cent[j * 3 + 0], cj1 = cent[j * 3 + 1], cj2 = cent[j * 3 + 2];
    float s0 = 0.f, s1 = 0.f, s2 = 0.f;
    for (int i = lane; i < j; i += 64) {
      float c0 = cent[i * 3 + 0], c1 = cent[i * 3 + 1], c2 = cent[i * 3 + 2];
      s0 += c0 * fabsf(c0 - cj0);
      s1 += c1 * fabsf(c1 - cj1);
      s2 += c2 * fabsf(c2 - cj2);
    }
#pragma unroll
    for (int d = 32; d > 0; d >>= 1) {
      s0 += __shfl_down(s0, d);
      s1 += __shfl_down(s1, d);
      s2 += __shfl_down(s2, d);
    }
    if (lane == 0) {
      float idg = invdeg(j);
      n1[j * 35 + 32] = s0 * idg;
      n1[j * 35 + 33] = s1 * idg;
      n1[j * 35 + 34] = s2 * idg;
    }
  }
}

// K2: h1[n,o] = sum_f h[n,f]*Ws1[f,o] + n1[n,f]*Wn1[f,o] + b1[o];  h = [x | cent]
__global__ __launch_bounds__(256) void k_h1(const float* __restrict__ x,
                                            const float* __restrict__ cent,
                                            const float* __restrict__ n1,
                                            const float* __restrict__ Ws1,
                                            const float* __restrict__ Wn1,
                                            const float* __restrict__ b1,
                                            float* __restrict__ h1) {
  const int tid = threadIdx.x;
  const int n = blockIdx.x * 4 + (tid >> 6);
  const int o = tid & 63;
  float acc = b1[o];
#pragma unroll
  for (int f = 0; f < 32; ++f)
    acc += x[n * 32 + f] * Ws1[f * 64 + o] + n1[n * 35 + f] * Wn1[f * 64 + o];
#pragma unroll
  for (int f = 32; f < 35; ++f)
    acc += cent[n * 3 + (f - 32)] * Ws1[f * 64 + o] + n1[n * 35 + f] * Wn1[f * 64 + o];
  h1[n * 64 + o] = acc;
}

// K3: per-feature exclusive scan of h1 rows -> neigh2 (scaled by invdeg)
__global__ __launch_bounds__(256) void k_scan_h1(const float* __restrict__ h1,
                                                 float* __restrict__ n2) {
  __shared__ float sc[256];
  const int tid = threadIdx.x;
  const int o = blockIdx.x;  // 0..63
  float sv[8];
  float ts = 0.f;
#pragma unroll
  for (int r = 0; r < 8; ++r) {
    int i = tid * 8 + r;
    float v = h1[i * 64 + o];
    sv[r] = v;
    ts += v;
  }
  sc[tid] = ts;
  __syncthreads();
  for (int off = 1; off < 256; off <<= 1) {
    float v = (tid >= off) ? sc[tid - off] : 0.f;
    __syncthreads();
    sc[tid] += v;
    __syncthreads();
  }
  float P = sc[tid] - ts;
#pragma unroll
  for (int r = 0; r < 8; ++r) {
    int i = tid * 8 + r;
    n2[i * 64 + o] = P * invdeg(i);
    P += sv[r];
  }
}

// K4: h2 then A = h2@Wm1[:32,:], B = h2@Wm1[32:,:] + bm1 (bias folded into B)
__global__ __launch_bounds__(256) void k_h2AB(const float* __restrict__ h1,
                                              const float* __restrict__ n2,
                                              const float* __restrict__ Ws2,
                                              const float* __restrict__ Wn2,
                                              const float* __restrict__ b2,
                                              const float* __restrict__ Wm1,
                                              const float* __restrict__ bm1,
                                              float* __restrict__ A,
                                              float* __restrict__ Bm) {
  __shared__ float h2s[8][32];
  const int tid = threadIdx.x;
  const int ln = tid >> 5;
  const int o = tid & 31;
  const int n = blockIdx.x * 8 + ln;
  float acc = b2[o];
#pragma unroll
  for (int f = 0; f < 64; ++f)
    acc += h1[n * 64 + f] * Ws2[f * 32 + o] + n2[n * 64 + f] * Wn2[f * 32 + o];
  h2s[ln][o] = acc;
  __syncthreads();
  float a = 0.f, b = bm1[o];
#pragma unroll
  for (int f = 0; f < 32; ++f) {
    float v = h2s[ln][f];
    a += v * Wm1[f * 32 + o];
    b += v * Wm1[(32 + f) * 32 + o];
  }
  A[n * 32 + o] = a;
  Bm[n * 32 + o] = b;
}

// K5: per-edge head. Tile: 8 i-rows x 256 j-cols. e = i*(4095-i)/2 + (j-i-1).
__global__ __launch_bounds__(256) void k_edges(const float* __restrict__ A,
                                               const float* __restrict__ Bm,
                                               const float* __restrict__ Wm2,
                                               const float* __restrict__ bm2,
                                               float2* __restrict__ out) {
  __shared__ float Bt[256 * 33];  // +1 pad: conflict-free row reads
  __shared__ float At[8 * 32];
  __shared__ float wm2s[64];
  __shared__ float bm2s[2];
  const int tid = threadIdx.x;
  const int j0 = blockIdx.x * 256;
  const int i0 = blockIdx.y * 8;
  if (i0 >= j0 + 255) return;  // block-uniform: no j > i in tile
  // stage B tile (coalesced global, padded LDS)
#pragma unroll
  for (int k = 0; k < 32; ++k) {
    int idx = tid + k * 256;
    int jj = idx >> 5, f = idx & 31;
    Bt[jj * 33 + f] = Bm[(j0 + jj) * 32 + f];
  }
  {
    int ii = tid >> 5, f = tid & 31;
    At[ii * 32 + f] = A[(i0 + ii) * 32 + f];
  }
  if (tid < 64) wm2s[tid] = Wm2[tid];
  if (tid < 2) bm2s[tid] = bm2[tid];
  __syncthreads();
  const int j = j0 + tid;
  float Br[32];
#pragma unroll
  for (int f = 0; f < 32; ++f) Br[f] = Bt[tid * 33 + f];
  const float bb0 = bm2s[0], bb1 = bm2s[1];
#pragma unroll
  for (int ii = 0; ii < 8; ++ii) {
    int i = i0 + ii;
    if (i >= j) continue;
    float l0 = bb0, l1 = bb1;
#pragma unroll
    for (int f = 0; f < 32; ++f) {
      float hv = At[ii * 32 + f] + Br[f];
      hv = fmaxf(hv, 0.f);
      l0 += hv * wm2s[f * 2];
      l1 += hv * wm2s[f * 2 + 1];
    }
    float t = __expf(l1 - l0);
    float p0 = 1.0f / (1.0f + t);
    float p1 = 1.0f - p0;
    int e = i * (2 * N_NODES - 1 - i) / 2 + (j - i - 1);
    out[e] = make_float2(p0, p1);
  }
}

extern "C" void kernel_launch(void* const* d_in, const int* in_sizes, int n_in,
                              void* d_out, int out_size, void* d_ws, size_t ws_size,
                              hipStream_t stream) {
  const float* x    = (const float*)d_in[0];
  const float* cent = (const float*)d_in[1];
  const float* Ws1  = (const float*)d_in[2];
  const float* Wn1  = (const float*)d_in[3];
  const float* b1   = (const float*)d_in[4];
  const float* Ws2  = (const float*)d_in[5];
  const float* Wn2  = (const float*)d_in[6];
  const float* b2   = (const float*)d_in[7];
  const float* Wm1  = (const float*)d_in[8];
  const float* bm1  = (const float*)d_in[9];
  const float* Wm2  = (const float*)d_in[10];
  const float* bm2  = (const float*)d_in[11];

  float* ws = (float*)d_ws;
  float* n1 = ws;                     // 2048*35 = 71680
  float* h1 = n1 + 2048 * 35;         // 2048*64 = 131072
  float* n2 = h1 + 2048 * 64;         // 2048*64 = 131072
  float* A  = n2 + 2048 * 64;         // 2048*32 = 65536
  float* Bm = A + 2048 * 32;          // 2048*32 = 65536  (total ~1.86 MB)

  k_edgefeat<<<544, 256, 0, stream>>>(x, cent, n1);
  k_h1<<<512, 256, 0, stream>>>(x, cent, n1, Ws1, Wn1, b1, h1);
  k_scan_h1<<<64, 256, 0, stream>>>(h1, n2);
  k_h2AB<<<256, 256, 0, stream>>>(h1, n2, Ws2, Wn2, b2, Wm1, bm1, A, Bm);
  k_edges<<<dim3(8, 256), 256, 0, stream>>>(A, Bm, Wm2, bm2, (float2*)d_out);
}

// Round 2
// 127.970 us; speedup vs baseline: 1.0814x; 1.0814x over previous
//
#include <hip/hip_runtime.h>
#include <math.h>

#define N_NODES 2048
#define N1S 36  // padded n1 row stride (16B-aligned rows: 36*4=144, 144%16==0)

__device__ __forceinline__ float invdeg(int j) { return j > 0 ? 1.0f / (float)j : 0.0f; }

// K1: blocks 0..31: per-feature exclusive scan of x[i,f]^2/||x_i|| -> n1[:, f]
//     blocks 32..287: 4 waves/block; wave w handles j in {w, 2047-w} (balanced),
//                     centroids staged in LDS (stride-3 coprime 32 -> conflict-free).
__global__ __launch_bounds__(256) void k_edgefeat(const float* __restrict__ x,
                                                  const float* __restrict__ cent,
                                                  float* __restrict__ n1) {
  const int tid = threadIdx.x;
  const int bx = blockIdx.x;
  if (bx < 32) {
    __shared__ float invn_s[N_NODES];
    __shared__ float sc[256];
    const int f = bx;
    for (int r = 0; r < 8; ++r) {
      int n = tid + 256 * r;
      const float4* xp = (const float4*)(x + n * 32);
      float s = 0.f;
#pragma unroll
      for (int q = 0; q < 8; ++q) {
        float4 v = xp[q];
        s += v.x * v.x + v.y * v.y + v.z * v.z + v.w * v.w;
      }
      invn_s[n] = rsqrtf(s);
    }
    __syncthreads();
    float sv[8], xv[8];
    float ts = 0.f;
#pragma unroll
    for (int r = 0; r < 8; ++r) {
      int i = tid * 8 + r;
      float xf = x[i * 32 + f];
      xv[r] = xf;
      float s = xf * xf * invn_s[i];
      sv[r] = s;
      ts += s;
    }
    sc[tid] = ts;
    __syncthreads();
    for (int off = 1; off < 256; off <<= 1) {
      float v = (tid >= off) ? sc[tid - off] : 0.f;
      __syncthreads();
      sc[tid] += v;
      __syncthreads();
    }
    float P = sc[tid] - ts;  // exclusive prefix of thread-chunk sums
#pragma unroll
    for (int r = 0; r < 8; ++r) {
      int i = tid * 8 + r;
      n1[i * N1S + f] = P * xv[r] * invn_s[i] * invdeg(i);
      P += sv[r];
    }
  } else {
    __shared__ float cs[N_NODES * 3];  // 24 KB
    // coalesced float4 stage: 6144 floats = 1536 float4
    const float4* cp = (const float4*)cent;
    float4* csp = (float4*)cs;
#pragma unroll
    for (int q = 0; q < 6; ++q) csp[tid + 256 * q] = cp[tid + 256 * q];
    __syncthreads();
    const int w = (bx - 32) * 4 + (tid >> 6);  // 0..1023
    const int lane = tid & 63;
#pragma unroll
    for (int pick = 0; pick < 2; ++pick) {
      const int j = pick ? (2047 - w) : w;
      const float cj0 = cs[j * 3 + 0], cj1 = cs[j * 3 + 1], cj2 = cs[j * 3 + 2];
      float s0 = 0.f, s1 = 0.f, s2 = 0.f;
      for (int i = lane; i < j; i += 64) {
        float c0 = cs[i * 3 + 0], c1 = cs[i * 3 + 1], c2 = cs[i * 3 + 2];
        s0 += c0 * fabsf(c0 - cj0);
        s1 += c1 * fabsf(c1 - cj1);
        s2 += c2 * fabsf(c2 - cj2);
      }
#pragma unroll
      for (int d = 32; d > 0; d >>= 1) {
        s0 += __shfl_down(s0, d);
        s1 += __shfl_down(s1, d);
        s2 += __shfl_down(s2, d);
      }
      if (lane == 0) {
        float idg = invdeg(j);
        n1[j * N1S + 32] = s0 * idg;
        n1[j * N1S + 33] = s1 * idg;
        n1[j * N1S + 34] = s2 * idg;
      }
    }
  }
}

// K2: h1[n,o] = h[n,:]@Ws1[:,o] + n1[n,:]@Wn1[:,o] + b1[o].  Wave-per-node,
// node rows via uniform s_load (readfirstlane), weights coalesced v-loads.
__global__ __launch_bounds__(256) void k_h1(const float* __restrict__ x,
                                            const float* __restrict__ cent,
                                            const float* __restrict__ n1,
                                            const float* __restrict__ Ws1,
                                            const float* __restrict__ Wn1,
                                            const float* __restrict__ b1,
                                            float* __restrict__ h1) {
  const int tid = threadIdx.x;
  const int n = __builtin_amdgcn_readfirstlane(blockIdx.x * 4 + (tid >> 6));
  const int o = tid & 63;
  float acc = b1[o];
  const float4* xr = (const float4*)(x + n * 32);
  const float4* nr = (const float4*)(n1 + n * N1S);
#pragma unroll
  for (int q = 0; q < 8; ++q) {
    float4 xv = xr[q];
    float4 nv = nr[q];
    acc += xv.x * Ws1[(4 * q + 0) * 64 + o] + nv.x * Wn1[(4 * q + 0) * 64 + o];
    acc += xv.y * Ws1[(4 * q + 1) * 64 + o] + nv.y * Wn1[(4 * q + 1) * 64 + o];
    acc += xv.z * Ws1[(4 * q + 2) * 64 + o] + nv.z * Wn1[(4 * q + 2) * 64 + o];
    acc += xv.w * Ws1[(4 * q + 3) * 64 + o] + nv.w * Wn1[(4 * q + 3) * 64 + o];
  }
  {
    float4 nv = nr[8];  // floats 32..35 (35 is pad, unused)
    float c0 = cent[n * 3 + 0], c1 = cent[n * 3 + 1], c2 = cent[n * 3 + 2];
    acc += c0 * Ws1[32 * 64 + o] + nv.x * Wn1[32 * 64 + o];
    acc += c1 * Ws1[33 * 64 + o] + nv.y * Wn1[33 * 64 + o];
    acc += c2 * Ws1[34 * 64 + o] + nv.z * Wn1[34 * 64 + o];
  }
  h1[n * 64 + o] = acc;
}

// K3: per-feature exclusive scan of h1 rows -> n2 (scaled by invdeg)
__global__ __launch_bounds__(256) void k_scan_h1(const float* __restrict__ h1,
                                                 float* __restrict__ n2) {
  __shared__ float sc[256];
  const int tid = threadIdx.x;
  const int o = blockIdx.x;  // 0..63
  float sv[8];
  float ts = 0.f;
#pragma unroll
  for (int r = 0; r < 8; ++r) {
    int i = tid * 8 + r;
    float v = h1[i * 64 + o];
    sv[r] = v;
    ts += v;
  }
  sc[tid] = ts;
  __syncthreads();
  for (int off = 1; off < 256; off <<= 1) {
    float v = (tid >= off) ? sc[tid - off] : 0.f;
    __syncthreads();
    sc[tid] += v;
    __syncthreads();
  }
  float P = sc[tid] - ts;
#pragma unroll
  for (int r = 0; r < 8; ++r) {
    int i = tid * 8 + r;
    n2[i * 64 + o] = P * invdeg(i);
    P += sv[r];
  }
}

// K4: wave-per-node. Phase 1: h2[o] (both wave-halves compute it, uniform s_loads
// for h1/n2 rows). Phase 2: half 0 -> A[n,o]=h2@Wm1[:32,o], half 1 -> Bm[n,o]=h2@Wm1[32:,o]+bm1[o].
__global__ __launch_bounds__(256) void k_h2AB(const float* __restrict__ h1,
                                              const float* __restrict__ n2,
                                              const float* __restrict__ Ws2,
                                              const float* __restrict__ Wn2,
                                              const float* __restrict__ b2,
                                              const float* __restrict__ Wm1,
                                              const float* __restrict__ bm1,
                                              float* __restrict__ A,
                                              float* __restrict__ Bm) {
  __shared__ float h2s[4][32];
  const int tid = threadIdx.x;
  const int wv = tid >> 6;
  const int lane = tid & 63;
  const int o = lane & 31;
  const int half = lane >> 5;
  const int n = __builtin_amdgcn_readfirstlane(blockIdx.x * 4 + wv);
  float acc = b2[o];
#pragma unroll
  for (int f = 0; f < 64; ++f)
    acc += h1[n * 64 + f] * Ws2[f * 32 + o] + n2[n * 64 + f] * Wn2[f * 32 + o];
  h2s[wv][o] = acc;  // both halves write identical value
  __syncthreads();
  float r = half ? bm1[o] : 0.f;
#pragma unroll
  for (int f = 0; f < 32; ++f)
    r += h2s[wv][f] * Wm1[(half * 32 + f) * 32 + o];
  if (half)
    Bm[n * 32 + o] = r;
  else
    A[n * 32 + o] = r;
}

// K5: per-edge head, LDS-free. Tile 8 i-rows x 256 j-cols; thread owns j.
// A/Wm2/bm2 reads are block-uniform -> s_load (SMEM pipe); B row in VGPRs.
__global__ __launch_bounds__(256) void k_edges(const float* __restrict__ A,
                                               const float* __restrict__ Bm,
                                               const float* __restrict__ Wm2,
                                               const float* __restrict__ bm2,
                                               float2* __restrict__ out) {
  const int tid = threadIdx.x;
  const int j0 = blockIdx.x * 256;
  const int i0 = blockIdx.y * 8;
  if (i0 >= j0 + 255) return;  // tile entirely below diagonal
  const int j = j0 + tid;
  float Br[32];
  const float4* bp = (const float4*)(Bm + j * 32);
#pragma unroll
  for (int q = 0; q < 8; ++q) {
    float4 v = bp[q];
    Br[4 * q + 0] = v.x;
    Br[4 * q + 1] = v.y;
    Br[4 * q + 2] = v.z;
    Br[4 * q + 3] = v.w;
  }
  const float bb0 = bm2[0], bb1 = bm2[1];
  float l0[8], l1[8];
#pragma unroll
  for (int ii = 0; ii < 8; ++ii) {
    l0[ii] = bb0;
    l1[ii] = bb1;
  }
#pragma unroll
  for (int f = 0; f < 32; ++f) {
    const float w0 = Wm2[f * 2], w1 = Wm2[f * 2 + 1];  // uniform -> s_load
    const float br = Br[f];
#pragma unroll
    for (int ii = 0; ii < 8; ++ii) {
      float hv = fmaxf(A[(i0 + ii) * 32 + f] + br, 0.f);  // A uniform -> s_load
      l0[ii] += hv * w0;
      l1[ii] += hv * w1;
    }
  }
#pragma unroll
  for (int ii = 0; ii < 8; ++ii) {
    int i = i0 + ii;
    if (i >= j) continue;
    float t = __expf(l1[ii] - l0[ii]);
    float p0 = 1.0f / (1.0f + t);
    int e = i * (2 * N_NODES - 1 - i) / 2 + (j - i - 1);
    out[e] = make_float2(p0, 1.0f - p0);
  }
}

extern "C" void kernel_launch(void* const* d_in, const int* in_sizes, int n_in,
                              void* d_out, int out_size, void* d_ws, size_t ws_size,
                              hipStream_t stream) {
  const float* x    = (const float*)d_in[0];
  const float* cent = (const float*)d_in[1];
  const float* Ws1  = (const float*)d_in[2];
  const float* Wn1  = (const float*)d_in[3];
  const float* b1   = (const float*)d_in[4];
  const float* Ws2  = (const float*)d_in[5];
  const float* Wn2  = (const float*)d_in[6];
  const float* b2   = (const float*)d_in[7];
  const float* Wm1  = (const float*)d_in[8];
  const float* bm1  = (const float*)d_in[9];
  const float* Wm2  = (const float*)d_in[10];
  const float* bm2  = (const float*)d_in[11];

  float* ws = (float*)d_ws;
  float* n1 = ws;                      // 2048*36 = 73728
  float* h1 = n1 + 2048 * N1S;         // 2048*64 = 131072
  float* n2 = h1 + 2048 * 64;          // 2048*64 = 131072
  float* A  = n2 + 2048 * 64;          // 2048*32 = 65536
  float* Bm = A + 2048 * 32;           // 2048*32 = 65536  (~1.9 MB total)

  k_edgefeat<<<288, 256, 0, stream>>>(x, cent, n1);
  k_h1<<<512, 256, 0, stream>>>(x, cent, n1, Ws1, Wn1, b1, h1);
  k_scan_h1<<<64, 256, 0, stream>>>(h1, n2);
  k_h2AB<<<512, 256, 0, stream>>>(h1, n2, Ws2, Wn2, b2, Wm1, bm1, A, Bm);
  k_edges<<<dim3(8, 256), 256, 0, stream>>>(A, Bm, Wm2, bm2, (float2*)d_out);
}

// Round 3
// 119.907 us; speedup vs baseline: 1.1541x; 1.0672x over previous
//
#include <hip/hip_runtime.h>
#include <math.h>

#define N_NODES 2048
#define N1S 36  // padded n1 row stride (16B-aligned rows)

__device__ __forceinline__ float invdeg(int j) { return j > 0 ? 1.0f / (float)j : 0.0f; }

// K1: blocks 0..31: per-feature exclusive scan of x[i,f]^2/||x_i|| -> n1[:, f]
//     blocks 32..287: 4 waves/block; wave w handles j in {w, 2047-w} (balanced),
//                     centroids staged in LDS.
__global__ __launch_bounds__(256) void k_edgefeat(const float* __restrict__ x,
                                                  const float* __restrict__ cent,
                                                  float* __restrict__ n1) {
  const int tid = threadIdx.x;
  const int bx = blockIdx.x;
  if (bx < 32) {
    __shared__ float invn_s[N_NODES];
    __shared__ float sc[256];
    const int f = bx;
    for (int r = 0; r < 8; ++r) {
      int n = tid + 256 * r;
      const float4* xp = (const float4*)(x + n * 32);
      float s = 0.f;
#pragma unroll
      for (int q = 0; q < 8; ++q) {
        float4 v = xp[q];
        s += v.x * v.x + v.y * v.y + v.z * v.z + v.w * v.w;
      }
      invn_s[n] = rsqrtf(s);
    }
    __syncthreads();
    float sv[8], xv[8];
    float ts = 0.f;
#pragma unroll
    for (int r = 0; r < 8; ++r) {
      int i = tid * 8 + r;
      float xf = x[i * 32 + f];
      xv[r] = xf;
      float s = xf * xf * invn_s[i];
      sv[r] = s;
      ts += s;
    }
    sc[tid] = ts;
    __syncthreads();
    for (int off = 1; off < 256; off <<= 1) {
      float v = (tid >= off) ? sc[tid - off] : 0.f;
      __syncthreads();
      sc[tid] += v;
      __syncthreads();
    }
    float P = sc[tid] - ts;  // exclusive prefix of thread-chunk sums
#pragma unroll
    for (int r = 0; r < 8; ++r) {
      int i = tid * 8 + r;
      n1[i * N1S + f] = P * xv[r] * invn_s[i] * invdeg(i);
      P += sv[r];
    }
  } else {
    __shared__ float cs[N_NODES * 3];  // 24 KB
    const float4* cp = (const float4*)cent;
    float4* csp = (float4*)cs;
#pragma unroll
    for (int q = 0; q < 6; ++q) csp[tid + 256 * q] = cp[tid + 256 * q];
    __syncthreads();
    const int w = (bx - 32) * 4 + (tid >> 6);  // 0..1023
    const int lane = tid & 63;
#pragma unroll
    for (int pick = 0; pick < 2; ++pick) {
      const int j = pick ? (2047 - w) : w;
      const float cj0 = cs[j * 3 + 0], cj1 = cs[j * 3 + 1], cj2 = cs[j * 3 + 2];
      float s0 = 0.f, s1 = 0.f, s2 = 0.f;
      for (int i = lane; i < j; i += 64) {
        float c0 = cs[i * 3 + 0], c1 = cs[i * 3 + 1], c2 = cs[i * 3 + 2];
        s0 += c0 * fabsf(c0 - cj0);
        s1 += c1 * fabsf(c1 - cj1);
        s2 += c2 * fabsf(c2 - cj2);
      }
#pragma unroll
      for (int d = 32; d > 0; d >>= 1) {
        s0 += __shfl_down(s0, d);
        s1 += __shfl_down(s1, d);
        s2 += __shfl_down(s2, d);
      }
      if (lane == 0) {
        float idg = invdeg(j);
        n1[j * N1S + 32] = s0 * idg;
        n1[j * N1S + 33] = s1 * idg;
        n1[j * N1S + 34] = s2 * idg;
      }
    }
  }
}

// K2: h1[n,o] = h[n,:]@Ws1[:,o] + n1[n,:]@Wn1[:,o] + b1[o].  Wave-per-node.
// Also writes column-major copy h1T[o*2048+n] (scattered stores are
// fire-and-forget) so K3's scan reads are coalesced.
__global__ __launch_bounds__(256) void k_h1(const float* __restrict__ x,
                                            const float* __restrict__ cent,
                                            const float* __restrict__ n1,
                                            const float* __restrict__ Ws1,
                                            const float* __restrict__ Wn1,
                                            const float* __restrict__ b1,
                                            float* __restrict__ h1,
                                            float* __restrict__ h1T) {
  const int tid = threadIdx.x;
  const int n = __builtin_amdgcn_readfirstlane(blockIdx.x * 4 + (tid >> 6));
  const int o = tid & 63;
  float acc = b1[o];
  const float4* xr = (const float4*)(x + n * 32);
  const float4* nr = (const float4*)(n1 + n * N1S);
#pragma unroll
  for (int q = 0; q < 8; ++q) {
    float4 xv = xr[q];
    float4 nv = nr[q];
    acc += xv.x * Ws1[(4 * q + 0) * 64 + o] + nv.x * Wn1[(4 * q + 0) * 64 + o];
    acc += xv.y * Ws1[(4 * q + 1) * 64 + o] + nv.y * Wn1[(4 * q + 1) * 64 + o];
    acc += xv.z * Ws1[(4 * q + 2) * 64 + o] + nv.z * Wn1[(4 * q + 2) * 64 + o];
    acc += xv.w * Ws1[(4 * q + 3) * 64 + o] + nv.w * Wn1[(4 * q + 3) * 64 + o];
  }
  {
    float4 nv = nr[8];  // floats 32..35 (35 is pad, unused)
    float c0 = cent[n * 3 + 0], c1 = cent[n * 3 + 1], c2 = cent[n * 3 + 2];
    acc += c0 * Ws1[32 * 64 + o] + nv.x * Wn1[32 * 64 + o];
    acc += c1 * Ws1[33 * 64 + o] + nv.y * Wn1[33 * 64 + o];
    acc += c2 * Ws1[34 * 64 + o] + nv.z * Wn1[34 * 64 + o];
  }
  h1[n * 64 + o] = acc;
  h1T[o * N_NODES + n] = acc;
}

// K3: per-feature exclusive scan of h1 columns -> n2 (scaled by invdeg).
// Reads coalesced from h1T; writes n2 row-major (scattered stores, latency-tolerant).
__global__ __launch_bounds__(256) void k_scan_h1(const float* __restrict__ h1T,
                                                 float* __restrict__ n2) {
  __shared__ float sc[256];
  const int tid = threadIdx.x;
  const int o = blockIdx.x;  // 0..63
  float sv[8];
  const float4* colp = (const float4*)(h1T + o * N_NODES);
  float4 a = colp[2 * tid];
  float4 b = colp[2 * tid + 1];
  sv[0] = a.x; sv[1] = a.y; sv[2] = a.z; sv[3] = a.w;
  sv[4] = b.x; sv[5] = b.y; sv[6] = b.z; sv[7] = b.w;
  float ts = 0.f;
#pragma unroll
  for (int r = 0; r < 8; ++r) ts += sv[r];
  sc[tid] = ts;
  __syncthreads();
  for (int off = 1; off < 256; off <<= 1) {
    float v = (tid >= off) ? sc[tid - off] : 0.f;
    __syncthreads();
    sc[tid] += v;
    __syncthreads();
  }
  float P = sc[tid] - ts;
#pragma unroll
  for (int r = 0; r < 8; ++r) {
    int i = tid * 8 + r;
    n2[i * 64 + o] = P * invdeg(i);
    P += sv[r];
  }
}

// K4: wave-per-node. Phase 1: h2[o] (both wave-halves compute it). Phase 2:
// half 0 -> A[n,o]=h2@Wm1[:32,o], half 1 -> Bm[n,o]=h2@Wm1[32:,o]+bm1[o].
__global__ __launch_bounds__(256) void k_h2AB(const float* __restrict__ h1,
                                              const float* __restrict__ n2,
                                              const float* __restrict__ Ws2,
                                              const float* __restrict__ Wn2,
                                              const float* __restrict__ b2,
                                              const float* __restrict__ Wm1,
                                              const float* __restrict__ bm1,
                                              float* __restrict__ A,
                                              float* __restrict__ Bm) {
  __shared__ float h2s[4][32];
  const int tid = threadIdx.x;
  const int wv = tid >> 6;
  const int lane = tid & 63;
  const int o = lane & 31;
  const int half = lane >> 5;
  const int n = __builtin_amdgcn_readfirstlane(blockIdx.x * 4 + wv);
  float acc = b2[o];
#pragma unroll
  for (int f = 0; f < 64; ++f)
    acc += h1[n * 64 + f] * Ws2[f * 32 + o] + n2[n * 64 + f] * Wn2[f * 32 + o];
  h2s[wv][o] = acc;  // both halves write identical value
  __syncthreads();
  float r = half ? bm1[o] : 0.f;
#pragma unroll
  for (int f = 0; f < 32; ++f)
    r += h2s[wv][f] * Wm1[(half * 32 + f) * 32 + o];
  if (half)
    Bm[n * 32 + o] = r;
  else
    A[n * 32 + o] = r;
}

// K5: per-edge head, LDS-free, logit-difference form:
// p0 = 1/(1+exp(db + sum_f relu(A[i,f]+B[j,f]) * (w1[f]-w0[f]))).
// Tile 8 i-rows x 256 j-cols; thread owns j; A-row + wd are wave-uniform (scalar).
__global__ __launch_bounds__(256) void k_edges(const float* __restrict__ A,
                                               const float* __restrict__ Bm,
                                               const float* __restrict__ Wm2,
                                               const float* __restrict__ bm2,
                                               float2* __restrict__ out) {
  const int tid = threadIdx.x;
  const int j0 = blockIdx.x * 256;
  const int i0 = blockIdx.y * 8;
  if (i0 >= j0 + 255) return;  // tile entirely below diagonal
  const int j = j0 + tid;
  float Br[32];
  const float4* bp = (const float4*)(Bm + j * 32);
#pragma unroll
  for (int q = 0; q < 8; ++q) {
    float4 v = bp[q];
    Br[4 * q + 0] = v.x;
    Br[4 * q + 1] = v.y;
    Br[4 * q + 2] = v.z;
    Br[4 * q + 3] = v.w;
  }
  float wd[32];
#pragma unroll
  for (int f = 0; f < 32; ++f)
    wd[f] = Wm2[f * 2 + 1] - Wm2[f * 2];  // uniform
  const float db = bm2[1] - bm2[0];
#pragma unroll
  for (int ii = 0; ii < 8; ++ii) {
    const int i = i0 + ii;
    const float* Ar = A + i * 32;  // uniform row -> scalar loads
    float d = db;
#pragma unroll
    for (int f = 0; f < 32; ++f)
      d += fmaxf(Ar[f] + Br[f], 0.f) * wd[f];
    if (i < j) {
      float p0 = 1.0f / (1.0f + __expf(d));
      int e = i * (2 * N_NODES - 1 - i) / 2 + (j - i - 1);
      out[e] = make_float2(p0, 1.0f - p0);
    }
  }
}

extern "C" void kernel_launch(void* const* d_in, const int* in_sizes, int n_in,
                              void* d_out, int out_size, void* d_ws, size_t ws_size,
                              hipStream_t stream) {
  const float* x    = (const float*)d_in[0];
  const float* cent = (const float*)d_in[1];
  const float* Ws1  = (const float*)d_in[2];
  const float* Wn1  = (const float*)d_in[3];
  const float* b1   = (const float*)d_in[4];
  const float* Ws2  = (const float*)d_in[5];
  const float* Wn2  = (const float*)d_in[6];
  const float* b2   = (const float*)d_in[7];
  const float* Wm1  = (const float*)d_in[8];
  const float* bm1  = (const float*)d_in[9];
  const float* Wm2  = (const float*)d_in[10];
  const float* bm2  = (const float*)d_in[11];

  float* ws  = (float*)d_ws;
  float* n1  = ws;                      // 2048*36
  float* h1  = n1 + 2048 * N1S;         // 2048*64
  float* h1T = h1 + 2048 * 64;          // 2048*64 (column-major copy)
  float* n2  = h1T + 2048 * 64;         // 2048*64
  float* A   = n2 + 2048 * 64;          // 2048*32
  float* Bm  = A + 2048 * 32;           // 2048*32  (~2.4 MB total)

  k_edgefeat<<<288, 256, 0, stream>>>(x, cent, n1);
  k_h1<<<512, 256, 0, stream>>>(x, cent, n1, Ws1, Wn1, b1, h1, h1T);
  k_scan_h1<<<64, 256, 0, stream>>>(h1T, n2);
  k_h2AB<<<512, 256, 0, stream>>>(h1, n2, Ws2, Wn2, b2, Wm1, bm1, A, Bm);
  k_edges<<<dim3(8, 256), 256, 0, stream>>>(A, Bm, Wm2, bm2, (float2*)d_out);
}